// Round 2
// baseline (9505.705 us; speedup 1.0000x reference)
//
#include <hip/hip_runtime.h>
#include <math.h>

typedef __attribute__((ext_vector_type(8))) short short8;
typedef __attribute__((ext_vector_type(4))) float f32x4;
typedef unsigned short ushort_t;
typedef unsigned int uint32;
typedef unsigned long long u64;

// ---------------- ws layout (float units) ----------------
#define WS_E      0        // e[4096]
#define WS_SCORES 4096     // scores[4096]
#define WS_ATT    8192     // att[4096]
#define WS_HID    12288    // hid[1024]
#define WS_HBUF   16384    // u64 hbuf[2 dir][2 parity][256]  (8 KB)

// ---------------- d_out layout (float units from base) ----------------
#define ENERGY_OFF   1024
#define XP_OFF       0          // bf16 xp[2][4096][1536]
#define OUTPUTS_OFF  6291456    // float outputs[4096][1024]
#define XBF_OFF      10485760   // bf16 x[4096][512]
#define WIH_OFF      11534336   // bf16 w_ih[3072][512]
#define WHH_OFF      12320768   // bf16 w_hh[2][1536][512]

__device__ __forceinline__ ushort_t f2bf(float f) {
  uint32 x = __float_as_uint(f);
  return (ushort_t)((x + 0x7fffu + ((x >> 16) & 1u)) >> 16);
}
__device__ __forceinline__ float bf2f(ushort_t u) {
  return __uint_as_float(((uint32)u) << 16);
}

// ============ K1: e[t], x_bf, weight bf16 conversion ============
__global__ __launch_bounds__(256) void k_prep(
    const float* __restrict__ query, const float* __restrict__ input,
    const float* __restrict__ fc_w, const float* __restrict__ fc_b,
    const float* __restrict__ w_ih_f, const float* __restrict__ w_ih_b,
    const float* __restrict__ w_hh_f, const float* __restrict__ w_hh_b,
    float* __restrict__ ws, float* __restrict__ outbase)
{
  int bid = blockIdx.x, tid = threadIdx.x;
  ushort_t* xbf   = (ushort_t*)(outbase + ENERGY_OFF + XBF_OFF);
  ushort_t* wihbf = (ushort_t*)(outbase + ENERGY_OFF + WIH_OFF);
  ushort_t* whhbf = (ushort_t*)(outbase + ENERGY_OFF + WHH_OFF);

  if (bid < 512) {
    int lane = tid & 63, wv = tid >> 6;
    float bconst = fc_b[0];
    const float4* w4 = (const float4*)fc_w;
    float4 b0 = w4[lane*2], b1 = w4[lane*2+1];
    for (int it = 0; it < 2; ++it) {
      int t = bid*8 + it*4 + wv;
      const float4* q4 = (const float4*)(query + (size_t)t*512);
      float4 a0 = q4[lane*2], a1 = q4[lane*2+1];
      float p = a0.x*b0.x + a0.y*b0.y + a0.z*b0.z + a0.w*b0.w
              + a1.x*b1.x + a1.y*b1.y + a1.z*b1.z + a1.w*b1.w;
      #pragma unroll
      for (int m = 1; m < 64; m <<= 1) p += __shfl_xor(p, m, 64);
      float e = p + bconst;
      if (lane == 0) ws[WS_E + t] = e;
      const float4* in4 = (const float4*)(input + (size_t)t*512);
      float4 x0 = in4[lane*2], x1 = in4[lane*2+1];
      short8 o;
      o[0]=(short)f2bf(e*x0.x); o[1]=(short)f2bf(e*x0.y);
      o[2]=(short)f2bf(e*x0.z); o[3]=(short)f2bf(e*x0.w);
      o[4]=(short)f2bf(e*x1.x); o[5]=(short)f2bf(e*x1.y);
      o[6]=(short)f2bf(e*x1.z); o[7]=(short)f2bf(e*x1.w);
      *(short8*)(xbf + (size_t)t*512 + lane*8) = o;
    }
  } else {
    size_t gid = (size_t)(bid - 512)*2048 + (size_t)tid*8;
    const float* src; ushort_t* dst; size_t doff, soff;
    if (gid < 786432)        { src = w_ih_f; dst = wihbf; doff = gid;          soff = gid; }
    else if (gid < 1572864)  { src = w_ih_b; dst = wihbf; doff = gid;          soff = gid - 786432; }
    else if (gid < 2359296)  { src = w_hh_f; dst = whhbf; doff = gid - 1572864; soff = gid - 1572864; }
    else                     { src = w_hh_b; dst = whhbf; doff = gid - 1572864; soff = gid - 2359296; }
    float4 v0 = *(const float4*)(src + soff);
    float4 v1 = *(const float4*)(src + soff + 4);
    short8 o;
    o[0]=(short)f2bf(v0.x); o[1]=(short)f2bf(v0.y); o[2]=(short)f2bf(v0.z); o[3]=(short)f2bf(v0.w);
    o[4]=(short)f2bf(v1.x); o[5]=(short)f2bf(v1.y); o[6]=(short)f2bf(v1.z); o[7]=(short)f2bf(v1.w);
    *(short8*)(dst + doff) = o;
  }
}

// ============ K2: xp GEMM  M=4096(t) x N=3072(j stacked f,b) x K=512 ============
__global__ __launch_bounds__(256) void k_xp_gemm(
    const float* __restrict__ b_ih_f, const float* __restrict__ b_ih_b,
    float* __restrict__ outbase)
{
  const ushort_t* xbf   = (const ushort_t*)(outbase + ENERGY_OFF + XBF_OFF);
  const ushort_t* wihbf = (const ushort_t*)(outbase + ENERGY_OFF + WIH_OFF);
  ushort_t* xpbf = (ushort_t*)(outbase + ENERGY_OFF + XP_OFF);

  int m0 = blockIdx.x * 64, n0 = blockIdx.y * 64;
  bool rev = (n0 >= 1536);
  __shared__ ushort_t As[64*40];
  __shared__ ushort_t Bs[64*40];
  int tid = threadIdx.x;
  int lane = tid & 63, wv = tid >> 6, l15 = lane & 15, quad = lane >> 4;
  int mw = (wv & 1)*32, nw = (wv >> 1)*32;
  f32x4 acc[2][2] = {};
  int lr = tid >> 2, lc = (tid & 3)*8;
  int t_eff = rev ? (4095 - (m0 + lr)) : (m0 + lr);
  const short8* asrc = (const short8*)(xbf + (size_t)t_eff*512 + lc);
  const short8* bsrc = (const short8*)(wihbf + (size_t)(n0 + lr)*512 + lc);

  for (int ks = 0; ks < 16; ++ks) {
    short8 av = asrc[ks*4];
    short8 bv = bsrc[ks*4];
    __syncthreads();
    *(short8*)(As + lr*40 + lc) = av;
    *(short8*)(Bs + lr*40 + lc) = bv;
    __syncthreads();
    short8 bf0 = *(const short8*)(Bs + (nw + l15)*40 + quad*8);
    short8 bf1 = *(const short8*)(Bs + (nw + 16 + l15)*40 + quad*8);
    #pragma unroll
    for (int mi = 0; mi < 2; ++mi) {
      short8 af = *(const short8*)(As + (mw + mi*16 + l15)*40 + quad*8);
      acc[mi][0] = __builtin_amdgcn_mfma_f32_16x16x32_bf16(af, bf0, acc[mi][0], 0, 0, 0);
      acc[mi][1] = __builtin_amdgcn_mfma_f32_16x16x32_bf16(af, bf1, acc[mi][1], 0, 0, 0);
    }
  }
  #pragma unroll
  for (int mi = 0; mi < 2; ++mi) {
    #pragma unroll
    for (int ni = 0; ni < 2; ++ni) {
      int j = n0 + nw + ni*16 + l15;
      int d2 = (j >= 1536) ? 1 : 0;
      int jj = j - d2*1536;
      float bias = d2 ? b_ih_b[jj] : b_ih_f[jj];
      int trow_base = m0 + mw + mi*16 + quad*4;
      #pragma unroll
      for (int r = 0; r < 4; ++r) {
        xpbf[((size_t)(d2*4096 + trow_base + r))*1536 + jj] = f2bf(acc[mi][ni][r] + bias);
      }
    }
  }
}

// ============ K3: persistent bidirectional GRU scan ============
// Active blocks: blk%8==0 -> fwd (XCD0 under round-robin), blk%8==4 -> bwd (XCD4).
// 8 WGs per direction, each owns 64 channels. WG = 320 threads:
//   waves 0..3: MFMA matvec (W_hh in VGPRs) + gates + publish + poll
//   wave 4: xp streaming (keeps its vmcnt off the exchange critical chain)
// Exchange: u64 hbuf[dir][parity][256], word = (bf16 h[2ch]<<32) | step tag.
__global__ __launch_bounds__(320, 1) void k_gru(
    const float* __restrict__ b_hh_f, const float* __restrict__ b_hh_b,
    float* __restrict__ ws, float* __restrict__ outbase)
{
  int blk = blockIdx.x;
  if (blk & 3) return;
  int d = (blk >> 2) & 1;
  int g = blk >> 3;

  const ushort_t* xpbf  = (const ushort_t*)(outbase + ENERGY_OFF + XP_OFF);
  const ushort_t* whhbf = (const ushort_t*)(outbase + ENERGY_OFF + WHH_OFF);
  float* outputs = outbase + ENERGY_OFF + OUTPUTS_OFF;
  u64* hb = ((u64*)(ws + WS_HBUF)) + d*512;

  int tid = threadIdx.x;
  int lane = tid & 63, wv = tid >> 6, l15 = lane & 15, quad = lane >> 4;
  int I0 = g * 64;
  int cbase = wv*16 + quad*4;      // meaningful for wv<4
  int C0 = I0 + cbase;

  __shared__ ushort_t h_bf[2][512];
  __shared__ ushort_t xpq[2][192];

  const ushort_t* xpd = xpbf + (size_t)d*4096*1536;

  short8 wfrag[3][16];
  float bhv[12];
  float hprev[4] = {0.f, 0.f, 0.f, 0.f};

  if (wv < 4) {
    const ushort_t* wbase = whhbf + (size_t)d*1536*512;
    const float* bhh = d ? b_hh_b : b_hh_f;
    #pragma unroll
    for (int g3 = 0; g3 < 3; ++g3) {
      const ushort_t* wrow = wbase + ((size_t)(g3*512 + I0 + wv*16 + l15))*512 + quad*8;
      #pragma unroll
      for (int kc = 0; kc < 16; ++kc)
        wfrag[g3][kc] = *(const short8*)(wrow + kc*32);
      float4 b4 = *(const float4*)(bhh + g3*512 + C0);
      bhv[g3*4+0] = b4.x; bhv[g3*4+1] = b4.y; bhv[g3*4+2] = b4.z; bhv[g3*4+3] = b4.w;
    }
    ((uint32*)h_bf)[tid] = 0;
    ((uint32*)h_bf)[tid + 256] = 0;
  }
  // wave 4 prologue: load xp[0]
  int xi = lane;
  u64 xreg = 0;
  if (wv == 4 && xi < 48) {
    xreg = *(const u64*)(xpd + ((size_t)(xi >> 4)*512 + I0 + (xi & 15)*4));
  }

  for (int t = 0; t < 4096; ++t) {
    int par = t & 1;
    if (wv < 4) {
      // poll foreign channel pairs (one u64 per thread, self-validating tag)
      if (t > 0 && (tid >> 5) != g) {
        uint32 want = (uint32)(t - 1);
        u64 v;
        do {
          v = __hip_atomic_load(hb + par*256 + tid, __ATOMIC_RELAXED, __HIP_MEMORY_SCOPE_AGENT);
        } while ((uint32)v != want);
        ((uint32*)h_bf[par])[tid] = (uint32)(v >> 32);
      }
    } else {
      // wave 4: commit xp[t] to LDS (vmcnt wait hits only this wave)
      if (xi < 48) *(u64*)(&xpq[par][xi*4]) = xreg;
    }
    __syncthreads();
    if (wv < 4) {
      f32x4 accr = {0.f,0.f,0.f,0.f}, accz = {0.f,0.f,0.f,0.f}, accn = {0.f,0.f,0.f,0.f};
      #pragma unroll
      for (int kc = 0; kc < 16; ++kc) {
        short8 hv = *(const short8*)(&h_bf[par][kc*32 + quad*8]);
        accr = __builtin_amdgcn_mfma_f32_16x16x32_bf16(wfrag[0][kc], hv, accr, 0, 0, 0);
        accz = __builtin_amdgcn_mfma_f32_16x16x32_bf16(wfrag[1][kc], hv, accz, 0, 0, 0);
        accn = __builtin_amdgcn_mfma_f32_16x16x32_bf16(wfrag[2][kc], hv, accn, 0, 0, 0);
      }
      // gates: every lane holds the full row results (cols broadcast), no LDS round-trip
      u64 xq0 = *(const u64*)(&xpq[par][cbase]);
      u64 xq1 = *(const u64*)(&xpq[par][64 + cbase]);
      u64 xq2 = *(const u64*)(&xpq[par][128 + cbase]);
      float hnew[4];
      #pragma unroll
      for (int r = 0; r < 4; ++r) {
        float xr = bf2f((ushort_t)(xq0 >> (r*16)));
        float xz = bf2f((ushort_t)(xq1 >> (r*16)));
        float xn = bf2f((ushort_t)(xq2 >> (r*16)));
        float hr = accr[r] + bhv[r];
        float hz = accz[r] + bhv[4 + r];
        float hn = accn[r] + bhv[8 + r];
        float rg = 1.0f/(1.0f + __expf(-(xr + hr)));
        float zg = 1.0f/(1.0f + __expf(-(xz + hz)));
        float ni = xn + rg*hn;
        float ng = 1.0f - 2.0f/(1.0f + __expf(2.0f*ni));   // tanh
        hnew[r] = (1.0f - zg)*ng + zg*hprev[r];
        hprev[r] = hnew[r];
      }
      if (l15 == 0) {
        int row = d ? (4095 - t) : t;
        float4 o; o.x = hnew[0]; o.y = hnew[1]; o.z = hnew[2]; o.w = hnew[3];
        *(float4*)(outputs + (size_t)row*1024 + d*512 + C0) = o;
        int par2 = (t + 1) & 1;
        ushort_t b0 = f2bf(hnew[0]), b1 = f2bf(hnew[1]);
        ushort_t b2 = f2bf(hnew[2]), b3 = f2bf(hnew[3]);
        uint32 lo = ((uint32)b1 << 16) | b0;
        uint32 hi = ((uint32)b3 << 16) | b2;
        // own channels -> next-parity LDS directly (no global round trip)
        *(u64*)(&h_bf[par2][C0]) = (((u64)hi) << 32) | lo;
        // publish tagged pairs for the other 7 WGs
        u64 p0 = (((u64)lo) << 32) | (uint32)t;
        u64 p1 = (((u64)hi) << 32) | (uint32)t;
        __hip_atomic_store(hb + par2*256 + (C0 >> 1),     p0, __ATOMIC_RELAXED, __HIP_MEMORY_SCOPE_AGENT);
        __hip_atomic_store(hb + par2*256 + (C0 >> 1) + 1, p1, __ATOMIC_RELAXED, __HIP_MEMORY_SCOPE_AGENT);
      }
    } else {
      // wave 4: prefetch xp[t+1]; latency overlaps other waves' poll
      if (xi < 48) {
        int tn = (t < 4095) ? (t + 1) : 4095;
        xreg = *(const u64*)(xpd + ((size_t)tn*1536 + (size_t)(xi >> 4)*512 + I0 + (xi & 15)*4));
      }
    }
  }
  if (wv < 4 && l15 == 0) {
    // hid = concat(hb_last, hf_last): d=1 -> [0..512), d=0 -> [512..1024)
    float4 o; o.x = hprev[0]; o.y = hprev[1]; o.z = hprev[2]; o.w = hprev[3];
    *(float4*)(ws + WS_HID + (1 - d)*512 + C0) = o;
  }
}

// ============ K4a: scores[t] = outputs[t]·hid * scale  (+ zero lin) ============
__global__ __launch_bounds__(256) void k_scores(float* __restrict__ ws, float* __restrict__ outbase)
{
  if (blockIdx.x == 256) {
    float4 z = {0.f,0.f,0.f,0.f};
    ((float4*)outbase)[threadIdx.x] = z;
    return;
  }
  const float* outputs = outbase + ENERGY_OFF + OUTPUTS_OFF;
  const float* hid = ws + WS_HID;
  int tid = threadIdx.x, lane = tid & 63, wv = tid >> 6;
  float4 hv[4];
  #pragma unroll
  for (int c = 0; c < 4; ++c) hv[c] = *(const float4*)(hid + lane*16 + c*4);
  const float scale = 0.03125f;  // 1/sqrt(1024)
  for (int it = 0; it < 4; ++it) {
    int t = blockIdx.x*16 + wv*4 + it;
    const float4* o4 = (const float4*)(outputs + (size_t)t*1024 + lane*16);
    float p = 0.f;
    #pragma unroll
    for (int c = 0; c < 4; ++c) {
      float4 o = o4[c];
      p += o.x*hv[c].x + o.y*hv[c].y + o.z*hv[c].z + o.w*hv[c].w;
    }
    #pragma unroll
    for (int m = 1; m < 64; m <<= 1) p += __shfl_xor(p, m, 64);
    if (lane == 0) ws[WS_SCORES + t] = p*scale;
  }
}

// ============ K4b: softmax over 4096 scores (one block) ============
__global__ __launch_bounds__(1024) void k_softmax(float* __restrict__ ws)
{
  int tid = threadIdx.x, lane = tid & 63, wv = tid >> 6;
  __shared__ float sm[16];
  float4 s = *(const float4*)(ws + WS_SCORES + tid*4);
  float mx = fmaxf(fmaxf(s.x, s.y), fmaxf(s.z, s.w));
  #pragma unroll
  for (int m = 1; m < 64; m <<= 1) mx = fmaxf(mx, __shfl_xor(mx, m, 64));
  if (lane == 0) sm[wv] = mx;
  __syncthreads();
  float bm = sm[0];
  #pragma unroll
  for (int i = 1; i < 16; ++i) bm = fmaxf(bm, sm[i]);
  float e0 = __expf(s.x - bm), e1 = __expf(s.y - bm);
  float e2 = __expf(s.z - bm), e3 = __expf(s.w - bm);
  float ps = e0 + e1 + e2 + e3;
  #pragma unroll
  for (int m = 1; m < 64; m <<= 1) ps += __shfl_xor(ps, m, 64);
  __syncthreads();
  if (lane == 0) sm[wv] = ps;
  __syncthreads();
  float tot = 0.f;
  #pragma unroll
  for (int i = 0; i < 16; ++i) tot += sm[i];
  float inv = 1.0f/tot;
  float4 a = {e0*inv, e1*inv, e2*inv, e3*inv};
  *(float4*)(ws + WS_ATT + tid*4) = a;
}

// ============ K4c: lin[j] = sum_t att[t]*outputs[t][j] ============
__global__ __launch_bounds__(256) void k_lin(const float* __restrict__ ws, float* __restrict__ outbase)
{
  const float* outputs = outbase + ENERGY_OFF + OUTPUTS_OFF;
  const float* att = ws + WS_ATT;
  int jb = blockIdx.x & 3, tseg = blockIdx.x >> 2;
  int j = jb*256 + threadIdx.x;
  float acc = 0.f;
  int t0 = tseg*256;
  for (int t = t0; t < t0 + 256; ++t)
    acc += att[t]*outputs[(size_t)t*1024 + j];
  atomicAdd(outbase + j, acc);
}

// ============ K5: energy = diag(e), overwrites the whole scratch region ============
__global__ __launch_bounds__(256) void k_energy(const float* __restrict__ ws, float* __restrict__ outbase)
{
  float* energy = outbase + ENERGY_OFF;
  int t = blockIdx.x;
  float e = ws[WS_E + t];
  #pragma unroll
  for (int k = 0; k < 4; ++k) {
    int c4 = (threadIdx.x + k*256)*4;
    float4 v = {0.f,0.f,0.f,0.f};
    if (t >= c4 && t < c4 + 4) ((float*)&v)[t - c4] = e;
    *(float4*)(energy + (size_t)t*4096 + c4) = v;
  }
}

extern "C" void kernel_launch(void* const* d_in, const int* in_sizes, int n_in,
                              void* d_out, int out_size, void* d_ws, size_t ws_size,
                              hipStream_t stream) {
  const float* input  = (const float*)d_in[0];
  const float* query  = (const float*)d_in[1];
  const float* fc_w   = (const float*)d_in[2];
  const float* fc_b   = (const float*)d_in[3];
  const float* w_ih_f = (const float*)d_in[4];
  const float* w_hh_f = (const float*)d_in[5];
  const float* b_ih_f = (const float*)d_in[6];
  const float* b_hh_f = (const float*)d_in[7];
  const float* w_ih_b = (const float*)d_in[8];
  const float* w_hh_b = (const float*)d_in[9];
  const float* b_ih_b = (const float*)d_in[10];
  const float* b_hh_b = (const float*)d_in[11];
  float* out = (float*)d_out;
  float* ws  = (float*)d_ws;

  hipLaunchKernelGGL(k_prep,    dim3(2048),   dim3(256),  0, stream,
                     query, input, fc_w, fc_b, w_ih_f, w_ih_b, w_hh_f, w_hh_b, ws, out);
  hipLaunchKernelGGL(k_xp_gemm, dim3(64, 48), dim3(256),  0, stream, b_ih_f, b_ih_b, out);
  hipLaunchKernelGGL(k_gru,     dim3(64),     dim3(320),  0, stream, b_hh_f, b_hh_b, ws, out);
  hipLaunchKernelGGL(k_scores,  dim3(257),    dim3(256),  0, stream, ws, out);
  hipLaunchKernelGGL(k_softmax, dim3(1),      dim3(1024), 0, stream, ws);
  hipLaunchKernelGGL(k_lin,     dim3(64),     dim3(256),  0, stream, ws, out);
  hipLaunchKernelGGL(k_energy,  dim3(4096),   dim3(256),  0, stream, ws, out);
}